// Round 13
// baseline (249.733 us; speedup 1.0000x reference)
//
#include <hip/hip_runtime.h>

#define NEG 0.2f
#define NEG_INF (-1e30f)

typedef __attribute__((ext_vector_type(8))) short bf16x8;
typedef __attribute__((ext_vector_type(4))) float f32x4;

__device__ __forceinline__ float leaky(float e) { return e > 0.f ? e : NEG * e; }

__device__ __forceinline__ unsigned short f2bf(float f) {
    unsigned int u = __float_as_uint(f);
    unsigned int r = u + 0x7fffu + ((u >> 16) & 1u);
    return (unsigned short)(r >> 16);
}
__device__ __forceinline__ float2 bf2f2(unsigned int u) {
    float2 r;
    r.x = __uint_as_float(u << 16);
    r.y = __uint_as_float(u & 0xffff0000u);
    return r;
}

// ---------------- fused prep: bucket-hist + x->bf16 + weight packing ----------------
__device__ __forceinline__ void pack_w(const float* __restrict__ W,
                                       unsigned short* __restrict__ Bp, int K, int N, int idx) {
    int i = idx & 7;
    int rest = idx >> 3;
    int lane = rest & 63;
    rest >>= 6;
    int KT = K / 32;
    int kt = rest % KT;
    int ct = rest / KT;
    int m = lane & 15, kb = lane >> 4;
    int k = kt * 32 + kb * 8 + i, col = ct * 16 + m;
    Bp[idx] = f2bf(W[(size_t)k * N + col]);
}

__global__ __launch_bounds__(256) void prep_kernel(const float* __restrict__ x,
                                                   unsigned short* __restrict__ xb, int n4,
                                                   const float* __restrict__ W1,
                                                   unsigned short* __restrict__ w1p,
                                                   const float* __restrict__ W2,
                                                   unsigned short* __restrict__ w2p,
                                                   const float* __restrict__ Wres,
                                                   unsigned short* __restrict__ wresp,
                                                   const int* __restrict__ dst, int E,
                                                   int* __restrict__ bucketCnt, int nbk,
                                                   int binBlks) {
    int b = blockIdx.x;
    if (b < binBlks) {
        __shared__ int hist[1600];
        for (int k = threadIdx.x; k < nbk; k += 256) hist[k] = 0;
        __syncthreads();
        int c0 = b * 4096;
        int cnt = min(4096, E - c0);
        for (int i = threadIdx.x; i < cnt; i += 256)
            atomicAdd(&hist[dst[c0 + i] >> 5], 1);
        __syncthreads();
        for (int k = threadIdx.x; k < nbk; k += 256) {
            int h = hist[k];
            if (h) atomicAdd(&bucketCnt[k], h);
        }
        return;
    }
    b -= binBlks;
    int nxb = (n4 + 255) / 256;
    if (b < nxb) {
        int i = b * 256 + threadIdx.x;
        if (i < n4) {
            float4 v = ((const float4*)x)[i];
            ushort4 o;
            o.x = f2bf(v.x); o.y = f2bf(v.y); o.z = f2bf(v.z); o.w = f2bf(v.w);
            ((ushort4*)xb)[i] = o;
        }
        return;
    }
    b -= nxb;
    if (b < 48) { pack_w(W1, w1p, 128, 96, b * 256 + threadIdx.x); return; }
    b -= 48;
    if (b < 48) { pack_w(W2, w2p, 96, 128, b * 256 + threadIdx.x); return; }
    b -= 48;
    if (b < 64) { pack_w(Wres, wresp, 128, 128, b * 256 + threadIdx.x); }
}

// ---------------- bucket scan (1563 elements, one block) + zero part ----------------
__global__ __launch_bounds__(1024) void scan_buckets(const int* __restrict__ bc,
                                                     int* __restrict__ pairBase,
                                                     int* __restrict__ bcur,
                                                     int* __restrict__ offs, int nbk, int n,
                                                     float* __restrict__ part) {
    __shared__ int buf[1024];
    __shared__ int carry;
    int tid = threadIdx.x;
    for (int i = tid; i < 64 * 256; i += 1024) part[i] = 0.f;
    if (tid == 0) carry = 0;
    __syncthreads();
    for (int base = 0; base < nbk; base += 1024) {
        int v = (base + tid < nbk) ? bc[base + tid] : 0;
        buf[tid] = v;
        __syncthreads();
        for (int s = 1; s < 1024; s <<= 1) {
            int t = (tid >= s) ? buf[tid - s] : 0;
            __syncthreads();
            buf[tid] += t;
            __syncthreads();
        }
        int incl = buf[tid];
        int tot = buf[1023];
        int c = carry;
        if (base + tid < nbk) {
            int ex = c + incl - v;  // exclusive prefix
            pairBase[base + tid] = ex;
            bcur[base + tid] = ex;
        }
        __syncthreads();
        if (tid == 0) carry = c + tot;
        __syncthreads();
    }
    if (tid == 0) {
        pairBase[nbk] = carry;
        offs[n] = carry;  // = E
    }
}

// ---------------- binned edge pass: LDS-staged bucket append ----------------
__global__ __launch_bounds__(256) void bin_kernel(const int* __restrict__ src,
                                                  const int* __restrict__ dst, int E,
                                                  int* __restrict__ bcur,
                                                  int2* __restrict__ pairBuf, int nb) {
    __shared__ int2 stage[4096];
    __shared__ int hist[1600];
    __shared__ int base[1600];
    for (int c0 = blockIdx.x * 4096; c0 < E; c0 += gridDim.x * 4096) {
        int cnt = min(4096, E - c0);
        for (int b = threadIdx.x; b < nb; b += 256) hist[b] = 0;
        __syncthreads();
        for (int i = threadIdx.x; i < cnt; i += 256) {
            int s = src[c0 + i], d = dst[c0 + i];
            stage[i] = make_int2(s, d);
            atomicAdd(&hist[d >> 5], 1);
        }
        __syncthreads();
        for (int b = threadIdx.x; b < nb; b += 256) {
            int h = hist[b];
            if (h) base[b] = atomicAdd(&bcur[b], h);
            hist[b] = 0;
        }
        __syncthreads();
        for (int i = threadIdx.x; i < cnt; i += 256) {
            int2 p = stage[i];
            int b = p.y >> 5;
            int off = atomicAdd(&hist[b], 1);
            pairBuf[base[b] + off] = p;
        }
        __syncthreads();
    }
}

// ---------------- MFMA GEMM body ----------------
template <int K, int N, int HEADS>
__device__ __forceinline__ void gemm_body(int w, const unsigned short* __restrict__ A,
                                          const unsigned short* __restrict__ Bp,
                                          const float* __restrict__ bias,
                                          unsigned short* __restrict__ outB,
                                          const float* __restrict__ asrc,
                                          const float* __restrict__ adst,
                                          float* __restrict__ a_s,
                                          float* __restrict__ a_d, int M) {
    constexpr int KT = K / 32, CT = N / 16;
    int row0 = w * 16;
    if (row0 >= M) return;
    int lane = threadIdx.x & 63;
    int m = lane & 15, kb = lane >> 4;
    const unsigned short* arow = A + (size_t)(row0 + m) * K + kb * 8;

    f32x4 acc[CT];
#pragma unroll
    for (int ct = 0; ct < CT; ++ct) acc[ct] = (f32x4){0.f, 0.f, 0.f, 0.f};

#pragma unroll
    for (int kt = 0; kt < KT; ++kt) {
        bf16x8 a = *(const bf16x8*)(arow + kt * 32);
#pragma unroll
        for (int ct = 0; ct < CT; ++ct) {
            bf16x8 b = *(const bf16x8*)(Bp + ((size_t)(ct * KT + kt) * 64 + lane) * 8);
            acc[ct] = __builtin_amdgcn_mfma_f32_16x16x32_bf16(a, b, acc[ct], 0, 0, 0);
        }
    }

#pragma unroll
    for (int r = 0; r < 4; ++r) {
        int row = row0 + kb * 4 + r;
#pragma unroll
        for (int ct = 0; ct < CT; ++ct) {
            int col = ct * 16 + m;
            float v = acc[ct][r] + (bias ? bias[col] : 0.f);
            outB[(size_t)row * N + col] = f2bf(v);
        }
    }

    if (HEADS > 0) {
        float asv[CT], adv[CT];
#pragma unroll
        for (int ct = 0; ct < CT; ++ct) {
            int col = ct * 16 + m;
            asv[ct] = asrc[col];
            adv[ct] = adst[col];
        }
        constexpr int TPH = CT / (HEADS > 0 ? HEADS : 1);
#pragma unroll
        for (int r = 0; r < 4; ++r) {
            int row = row0 + kb * 4 + r;
#pragma unroll
            for (int h = 0; h < HEADS; ++h) {
                float s = 0.f, d = 0.f;
#pragma unroll
                for (int t = 0; t < TPH; ++t) {
                    int ct = h * TPH + t;
                    s += acc[ct][r] * asv[ct];
                    d += acc[ct][r] * adv[ct];
                }
#pragma unroll
                for (int off = 1; off <= 8; off <<= 1) {
                    s += __shfl_xor(s, off);
                    d += __shfl_xor(d, off);
                }
                if (m == 0) {
                    a_s[(size_t)row * HEADS + h] = s;
                    a_d[(size_t)row * HEADS + h] = d;
                }
            }
        }
    }
}

// ---------------- phase2: passB (degree+offs+scatter) + gemm1 ----------------
__global__ __launch_bounds__(256) void phase2_kernel(
    const int2* __restrict__ pairBuf, const int* __restrict__ pairBase,
    const int* __restrict__ bcur, int* __restrict__ offs,
    int* __restrict__ csr, int nb,
    const unsigned short* __restrict__ xb,
    const unsigned short* __restrict__ w1p, unsigned short* __restrict__ h1b,
    const float* __restrict__ asrc1, const float* __restrict__ adst1,
    float* __restrict__ as1, float* __restrict__ ad1, int n, int passBlks) {
    int b = blockIdx.x;
    int lane = threadIdx.x & 63;
    int wid = threadIdx.x >> 6;
    if (b < passBlks) {
        __shared__ int cnt[4][32];
        int bk = b * 4 + wid;
        if (bk < nb) {
            int node0 = bk * 32;
            int lo = pairBase[bk], hi = bcur[bk];
            if (lane < 32) cnt[wid][lane] = 0;
            for (int i = lo + lane; i < hi; i += 64)
                atomicAdd(&cnt[wid][pairBuf[i].y & 31], 1);
            int myc = (lane < 32) ? cnt[wid][lane] : 0;
            int c = myc;
#pragma unroll
            for (int s = 1; s < 32; s <<= 1) {
                int t = __shfl_up(c, s);
                if (lane >= s && lane < 32) c += t;
            }
            int basePos = lo + c - myc;
            if (lane < 32) {
                if (node0 + lane < n) offs[node0 + lane] = basePos;
                cnt[wid][lane] = basePos;
            }
            for (int i = lo + lane; i < hi; i += 64) {
                int2 p = pairBuf[i];
                int pos = atomicAdd(&cnt[wid][p.y & 31], 1);
                csr[pos] = p.x;
            }
        }
        return;
    }
    b -= passBlks;
    gemm_body<128, 96, 3>(b * 4 + wid, xb, w1p, nullptr, h1b, asrc1, adst1, as1, ad1, n);
}

// gemm2 standalone wrapper
__global__ __launch_bounds__(256) void gemm2_kernel(const unsigned short* __restrict__ A,
                                                    const unsigned short* __restrict__ Bp,
                                                    unsigned short* __restrict__ outB,
                                                    const float* __restrict__ asrc,
                                                    const float* __restrict__ adst,
                                                    float* __restrict__ a_s,
                                                    float* __restrict__ a_d, int M) {
    gemm_body<96, 128, 1>(blockIdx.x * 4 + (threadIdx.x >> 6), A, Bp, nullptr, outB,
                          asrc, adst, a_s, a_d, M);
}

// ---------------- fused: gemm_res + gat1 (2 waves per node) ----------------
__global__ __launch_bounds__(256) void gat1_res_kernel(
    const unsigned short* __restrict__ h1b,
    const float* __restrict__ a_s, const float* __restrict__ a_d,
    const int* __restrict__ offs, const int* __restrict__ csr,
    const float* __restrict__ b1, unsigned short* __restrict__ out1b,
    const unsigned short* __restrict__ xb, const unsigned short* __restrict__ wresp,
    const float* __restrict__ bres, unsigned short* __restrict__ residb,
    int n, int gresBlks) {
    int b = blockIdx.x;
    int wid = threadIdx.x >> 6, lane = threadIdx.x & 63;
    if (b < gresBlks) {
        gemm_body<128, 128, 0>(b * 4 + wid, xb, wresp, bres, residb,
                               nullptr, nullptr, nullptr, nullptr, n);
        return;
    }
    b -= gresBlks;
    __shared__ int ssrc[4][64];
    __shared__ float se[4][3][64];
    __shared__ float pm[4][3];
    __shared__ float pden[4][3];
    __shared__ float2 pacc[2][48];
    int slot = wid >> 1, sub = wid & 1;
    int node = b * 2 + slot;
    bool valid = node < n;
    int beg = 0, end = 0;
    if (valid) { beg = offs[node]; end = offs[node + 1]; }
    int deg = end - beg;
    int half1 = (deg + 1) >> 1;
    int myBeg = beg + (sub ? half1 : 0);
    int myEnd = sub ? end : beg + half1;
    float ad0 = 0.f, ad1 = 0.f, ad2 = 0.f, es0 = 0.f, es1 = 0.f, es2 = 0.f;
    if (valid) {
        ad0 = a_d[node * 3 + 0]; ad1 = a_d[node * 3 + 1]; ad2 = a_d[node * 3 + 2];
        es0 = leaky(a_s[node * 3 + 0] + ad0);
        es1 = leaky(a_s[node * 3 + 1] + ad1);
        es2 = leaky(a_s[node * 3 + 2] + ad2);
    }
    int head = lane >> 4; if (head > 2) head = 2;

    // partial max over this wave's half of the edge list
    float m0 = NEG_INF, m1 = NEG_INF, m2 = NEG_INF;
    for (int j = myBeg + lane; j < myEnd; j += 64) {
        int s = csr[j];
        m0 = fmaxf(m0, leaky(a_s[s * 3 + 0] + ad0));
        m1 = fmaxf(m1, leaky(a_s[s * 3 + 1] + ad1));
        m2 = fmaxf(m2, leaky(a_s[s * 3 + 2] + ad2));
    }
#pragma unroll
    for (int sh = 32; sh >= 1; sh >>= 1) {
        m0 = fmaxf(m0, __shfl_xor(m0, sh));
        m1 = fmaxf(m1, __shfl_xor(m1, sh));
        m2 = fmaxf(m2, __shfl_xor(m2, sh));
    }
    if (lane == 0) { pm[wid][0] = m0; pm[wid][1] = m1; pm[wid][2] = m2; }
    __syncthreads();
    {
        int wA = slot * 2, wB = slot * 2 + 1;
        m0 = fmaxf(fmaxf(pm[wA][0], pm[wB][0]), es0);
        m1 = fmaxf(fmaxf(pm[wA][1], pm[wB][1]), es1);
        m2 = fmaxf(fmaxf(pm[wA][2], pm[wB][2]), es2);
    }

    float den0 = 0.f, den1 = 0.f, den2 = 0.f;
    float2 acc = make_float2(0.f, 0.f);
    for (int t0 = myBeg; t0 < myEnd; t0 += 64) {
        int cnt = min(64, myEnd - t0);
        int s = 0;
        float e0 = 0.f, e1 = 0.f, e2 = 0.f;
        if (lane < cnt) {
            s = csr[t0 + lane];
            e0 = __expf(leaky(a_s[s * 3 + 0] + ad0) - m0);
            e1 = __expf(leaky(a_s[s * 3 + 1] + ad1) - m1);
            e2 = __expf(leaky(a_s[s * 3 + 2] + ad2) - m2);
        }
        ssrc[wid][lane] = s;
        se[wid][0][lane] = e0; se[wid][1][lane] = e1; se[wid][2][lane] = e2;
        // den via lane-parallel shfl reduce
        float d0 = e0, d1 = e1, d2 = e2;
#pragma unroll
        for (int sh = 32; sh >= 1; sh >>= 1) {
            d0 += __shfl_xor(d0, sh);
            d1 += __shfl_xor(d1, sh);
            d2 += __shfl_xor(d2, sh);
        }
        den0 += d0; den1 += d1; den2 += d2;
        // gather (8-wide MLP)
        int jj = 0;
        for (; jj + 7 < cnt; jj += 8) {
            int sA[8]; float wA[8]; unsigned ph[8];
#pragma unroll
            for (int q = 0; q < 8; ++q) {
                sA[q] = ssrc[wid][jj + q];
                wA[q] = se[wid][head][jj + q];
            }
#pragma unroll
            for (int q = 0; q < 8; ++q)
                ph[q] = (lane < 48) ? *(const unsigned*)&h1b[(size_t)sA[q] * 96 + 2 * lane] : 0u;
#pragma unroll
            for (int q = 0; q < 8; ++q) {
                if (lane < 48) {
                    float2 h = bf2f2(ph[q]);
                    acc.x += wA[q] * h.x; acc.y += wA[q] * h.y;
                }
            }
        }
        for (; jj + 3 < cnt; jj += 4) {
            int sA[4]; float wA[4]; unsigned ph[4];
#pragma unroll
            for (int q = 0; q < 4; ++q) {
                sA[q] = ssrc[wid][jj + q];
                wA[q] = se[wid][head][jj + q];
            }
#pragma unroll
            for (int q = 0; q < 4; ++q)
                ph[q] = (lane < 48) ? *(const unsigned*)&h1b[(size_t)sA[q] * 96 + 2 * lane] : 0u;
#pragma unroll
            for (int q = 0; q < 4; ++q) {
                if (lane < 48) {
                    float2 h = bf2f2(ph[q]);
                    acc.x += wA[q] * h.x; acc.y += wA[q] * h.y;
                }
            }
        }
        for (; jj < cnt; ++jj) {
            int sA = ssrc[wid][jj];
            float wAq = se[wid][head][jj];
            if (lane < 48) {
                float2 ha = bf2f2(*(const unsigned*)&h1b[(size_t)sA * 96 + 2 * lane]);
                acc.x += wAq * ha.x; acc.y += wAq * ha.y;
            }
        }
    }

    // self-loop handled by sub0 wave
    if (sub == 0 && valid) {
        float w0 = __expf(es0 - m0), w1 = __expf(es1 - m1), w2 = __expf(es2 - m2);
        den0 += w0; den1 += w1; den2 += w2;
        if (lane < 48) {
            float2 hv0 = bf2f2(*(const unsigned*)&h1b[(size_t)node * 96 + 2 * lane]);
            float wS = (lane < 16) ? w0 : ((lane < 32) ? w1 : w2);
            acc.x += wS * hv0.x; acc.y += wS * hv0.y;
        }
    }
    if (lane == 0) { pden[wid][0] = den0; pden[wid][1] = den1; pden[wid][2] = den2; }
    if (sub == 1 && lane < 48) pacc[slot][lane] = acc;
    __syncthreads();
    if (sub == 0 && valid && lane < 48) {
        int wB = slot * 2 + 1;
        float2 pa = pacc[slot][lane];
        acc.x += pa.x; acc.y += pa.y;
        float den = (lane < 16) ? den0 + pden[wB][0]
                  : (lane < 32) ? den1 + pden[wB][1]
                                : den2 + pden[wB][2];
        float inv = 1.f / (den + 1e-16f);
        ushort2 o;
        o.x = f2bf(acc.x * inv + b1[2 * lane]);
        o.y = f2bf(acc.y * inv + b1[2 * lane + 1]);
        *(ushort2*)&out1b[(size_t)node * 96 + 2 * lane] = o;
    }
}

// gat2: 128 ch, 1 head; writes bf16 out2 AND accumulates BN partial sums.
__global__ __launch_bounds__(256) void gat2_agg(const unsigned short* __restrict__ h2b,
                                                const float* __restrict__ a_s,
                                                const float* __restrict__ a_d,
                                                const int* __restrict__ offs,
                                                const int* __restrict__ csr,
                                                const float* __restrict__ b2,
                                                unsigned short* __restrict__ out2b,
                                                float* __restrict__ part, int n) {
    __shared__ int ssrc[4][64];
    __shared__ float se[4][64];
    __shared__ float4 red[4][64];
    int wid = threadIdx.x >> 6;
    int node = blockIdx.x * 4 + wid;
    int lane = threadIdx.x & 63;
    float2 o = make_float2(0.f, 0.f);

    if (node < n) {
        int beg = offs[node], end = offs[node + 1];
        int deg = end - beg;
        float ad = a_d[node];
        float es = leaky(a_s[node] + ad);
        float2 hv0 = bf2f2(*(const unsigned int*)&h2b[(size_t)node * 128 + 2 * lane]);
        float den;
        float2 acc;

        if (deg <= 64) {
            int s = 0;
            float l = NEG_INF;
            if (lane < deg) {
                s = csr[beg + lane];
                l = leaky(a_s[s] + ad);
            }
            float m = l;
#pragma unroll
            for (int sh = 32; sh >= 1; sh >>= 1) m = fmaxf(m, __shfl_xor(m, sh));
            m = fmaxf(m, es);
            float e = (lane < deg) ? __expf(l - m) : 0.f;
            ssrc[wid][lane] = s;
            se[wid][lane] = e;
            float wSelf = __expf(es - m);
            den = wSelf;
            acc.x = wSelf * hv0.x; acc.y = wSelf * hv0.y;

            int jj = 0;
            for (; jj + 7 < deg; jj += 8) {
                int sA[8]; float wA[8]; unsigned ph[8];
#pragma unroll
                for (int q = 0; q < 8; ++q) {
                    sA[q] = ssrc[wid][jj + q];
                    wA[q] = se[wid][jj + q];
                }
#pragma unroll
                for (int q = 0; q < 8; ++q)
                    ph[q] = *(const unsigned*)&h2b[(size_t)sA[q] * 128 + 2 * lane];
                float dsum = 0.f;
#pragma unroll
                for (int q = 0; q < 8; ++q) {
                    dsum += wA[q];
                    float2 h = bf2f2(ph[q]);
                    acc.x += wA[q] * h.x; acc.y += wA[q] * h.y;
                }
                den += dsum;
            }
            for (; jj + 3 < deg; jj += 4) {
                int sA[4]; float wA[4]; unsigned ph[4];
#pragma unroll
                for (int q = 0; q < 4; ++q) {
                    sA[q] = ssrc[wid][jj + q];
                    wA[q] = se[wid][jj + q];
                }
#pragma unroll
                for (int q = 0; q < 4; ++q)
                    ph[q] = *(const unsigned*)&h2b[(size_t)sA[q] * 128 + 2 * lane];
                float dsum = 0.f;
#pragma unroll
                for (int q = 0; q < 4; ++q) {
                    dsum += wA[q];
                    float2 h = bf2f2(ph[q]);
                    acc.x += wA[q] * h.x; acc.y += wA[q] * h.y;
                }
                den += dsum;
            }
            for (; jj < deg; ++jj) {
                int sA = ssrc[wid][jj];
                float wA = se[wid][jj];
                den += wA;
                float2 ha = bf2f2(*(const unsigned*)&h2b[(size_t)sA * 128 + 2 * lane]);
                acc.x += wA * ha.x; acc.y += wA * ha.y;
            }
        } else {
            float m = es;
            for (int j = beg + lane; j < end; j += 64) {
                int s = csr[j];
                m = fmaxf(m, leaky(a_s[s] + ad));
            }
#pragma unroll
            for (int sh = 32; sh >= 1; sh >>= 1) m = fmaxf(m, __shfl_xor(m, sh));
            float wSelf = __expf(es - m);
            den = wSelf;
            acc.x = wSelf * hv0.x; acc.y = wSelf * hv0.y;
            for (int t0 = beg; t0 < end; t0 += 64) {
                int cnt = min(64, end - t0);
                int s = 0;
                float e = 0.f;
                if (lane < cnt) {
                    s = csr[t0 + lane];
                    e = __expf(leaky(a_s[s] + ad) - m);
                }
                ssrc[wid][lane] = s;
                se[wid][lane] = e;
                int jj = 0;
                for (; jj + 7 < cnt; jj += 8) {
                    int sA[8]; float wA[8]; unsigned ph[8];
#pragma unroll
                    for (int q = 0; q < 8; ++q) {
                        sA[q] = ssrc[wid][jj + q];
                        wA[q] = se[wid][jj + q];
                    }
#pragma unroll
                    for (int q = 0; q < 8; ++q)
                        ph[q] = *(const unsigned*)&h2b[(size_t)sA[q] * 128 + 2 * lane];
                    float dsum = 0.f;
#pragma unroll
                    for (int q = 0; q < 8; ++q) {
                        dsum += wA[q];
                        float2 h = bf2f2(ph[q]);
                        acc.x += wA[q] * h.x; acc.y += wA[q] * h.y;
                    }
                    den += dsum;
                }
                for (; jj < cnt; ++jj) {
                    int sA = ssrc[wid][jj];
                    float wA = se[wid][jj];
                    den += wA;
                    float2 ha = bf2f2(*(const unsigned*)&h2b[(size_t)sA * 128 + 2 * lane]);
                    acc.x += wA * ha.x; acc.y += wA * ha.y;
                }
            }
        }

        float inv = 1.f / (den + 1e-16f);
        o.x = acc.x * inv + b2[2 * lane];
        o.y = acc.y * inv + b2[2 * lane + 1];
        ushort2 ob;
        ob.x = f2bf(o.x); ob.y = f2bf(o.y);
        *(ushort2*)&out2b[(size_t)node * 128 + 2 * lane] = ob;
    }

    // ---- block-level BN partial reduction ----
    red[wid][lane] = make_float4(o.x, o.y, o.x * o.x, o.y * o.y);
    __syncthreads();
    if (wid == 0) {
        float4 a = red[0][lane], b = red[1][lane], c = red[2][lane], d = red[3][lane];
        float sx = a.x + b.x + c.x + d.x;
        float sy = a.y + b.y + c.y + d.y;
        float qx = a.z + b.z + c.z + d.z;
        float qy = a.w + b.w + c.w + d.w;
        float* p = part + (size_t)(blockIdx.x & 63) * 256;
        atomicAdd(&p[2 * lane + 0], sx);
        atomicAdd(&p[2 * lane + 1], sy);
        atomicAdd(&p[128 + 2 * lane + 0], qx);
        atomicAdd(&p[128 + 2 * lane + 1], qy);
    }
}

// ---------------- BN finalize ----------------
__global__ void bn_finalize(const float* __restrict__ part, const float* __restrict__ gamma,
                            const float* __restrict__ beta, float* __restrict__ ss, int n) {
    int c = threadIdx.x;  // 128
    float S = 0.f, Q = 0.f;
    for (int k = 0; k < 64; ++k) {
        S += part[(size_t)k * 256 + c];
        Q += part[(size_t)k * 256 + 128 + c];
    }
    float invN = 1.f / (float)n;
    float mu = S * invN;
    float var = Q * invN - mu * mu;
    float g = gamma[c] * rsqrtf(var + 1e-5f);
    ss[c] = g;
    ss[128 + c] = beta[c] - mu * g;
}

// ---------------- fused BN-normalize + ReLU + residual ----------------
__global__ void final_kernel(const unsigned short* __restrict__ out2b,
                             const unsigned short* __restrict__ residb,
                             const float* __restrict__ ss, float* __restrict__ out, int n) {
    int i = blockIdx.x * blockDim.x + threadIdx.x;
    if (i >= n * 32) return;
    int c0 = (i & 31) * 4;
    uint2 v = ((const uint2*)out2b)[i];
    uint2 r = ((const uint2*)residb)[i];
    float2 v01 = bf2f2(v.x), v23 = bf2f2(v.y);
    float2 r01 = bf2f2(r.x), r23 = bf2f2(r.y);
    float4 o;
    o.x = fmaxf(v01.x * ss[c0 + 0] + ss[128 + c0 + 0], 0.f) + r01.x;
    o.y = fmaxf(v01.y * ss[c0 + 1] + ss[128 + c0 + 1], 0.f) + r01.y;
    o.z = fmaxf(v23.x * ss[c0 + 2] + ss[128 + c0 + 2], 0.f) + r23.x;
    o.w = fmaxf(v23.y * ss[c0 + 3] + ss[128 + c0 + 3], 0.f) + r23.y;
    ((float4*)out)[i] = o;
}

extern "C" void kernel_launch(void* const* d_in, const int* in_sizes, int n_in,
                              void* d_out, int out_size, void* d_ws, size_t ws_size,
                              hipStream_t stream) {
    const float* x     = (const float*)d_in[0];
    const int*   ei    = (const int*)d_in[1];
    const float* W1    = (const float*)d_in[2];
    const float* asrc1 = (const float*)d_in[3];
    const float* adst1 = (const float*)d_in[4];
    const float* b1    = (const float*)d_in[5];
    const float* W2    = (const float*)d_in[6];
    const float* asrc2 = (const float*)d_in[7];
    const float* adst2 = (const float*)d_in[8];
    const float* b2    = (const float*)d_in[9];
    const float* gamma = (const float*)d_in[10];
    const float* beta  = (const float*)d_in[11];
    const float* Wres  = (const float*)d_in[12];
    const float* bres  = (const float*)d_in[13];

    const int n = in_sizes[0] / 128;  // 50000
    const int E = in_sizes[1] / 2;    // 800000

    char* ws = (char*)d_ws;
    size_t off = 0;
    auto alloc = [&](size_t bytes) {
        void* p = ws + off;
        off = (off + bytes + 255) & ~(size_t)255;
        return p;
    };
    float* as1  = (float*)alloc((size_t)n * 3 * 4);
    float* ad1  = (float*)alloc((size_t)n * 3 * 4);
    float* as2  = (float*)alloc((size_t)n * 4);
    float* ad2  = (float*)alloc((size_t)n * 4);
    float* part = (float*)alloc(64 * 256 * 4);
    float* ss   = (float*)alloc(256 * 4);
    unsigned short* xb     = (unsigned short*)alloc((size_t)n * 128 * 2);
    unsigned short* h1b    = (unsigned short*)alloc((size_t)n * 96 * 2);
    unsigned short* h2b    = (unsigned short*)alloc((size_t)n * 128 * 2);
    unsigned short* out1b  = (unsigned short*)alloc((size_t)n * 96 * 2);
    unsigned short* out2b  = (unsigned short*)alloc((size_t)n * 128 * 2);
    unsigned short* residb = (unsigned short*)alloc((size_t)n * 128 * 2);
    unsigned short* w1p    = (unsigned short*)alloc(128 * 96 * 2);
    unsigned short* w2p    = (unsigned short*)alloc(96 * 128 * 2);
    unsigned short* wresp  = (unsigned short*)alloc(128 * 128 * 2);
    int* offs      = (int*)alloc((size_t)(n + 1) * 4);
    int* bucketCnt = (int*)alloc(1600 * 4);
    int* pairBase  = (int*)alloc(1601 * 4);
    int* bcur      = (int*)alloc(1600 * 4);
    int2* pairBuf  = (int2*)alloc((size_t)E * 8);
    int* csr       = (int*)alloc((size_t)E * 4);

    hipMemsetAsync(bucketCnt, 0, 1600 * 4, stream);

    const int* srcIdx = ei;
    const int* dstIdx = ei + E;
    const int NB = (n + 31) / 32;           // 1563 buckets
    const int binBlks = (E + 4095) / 4096;  // 196

    const int nxb = (n * 32 + 255) / 256;
    prep_kernel<<<binBlks + nxb + 160, 256, 0, stream>>>(x, xb, n * 32, W1, w1p, W2, w2p,
                                                         Wres, wresp, dstIdx, E,
                                                         bucketCnt, NB, binBlks);

    scan_buckets<<<1, 1024, 0, stream>>>(bucketCnt, pairBase, bcur, offs, NB, n, part);

    bin_kernel<<<binBlks, 256, 0, stream>>>(srcIdx, dstIdx, E, bcur, pairBuf, NB);

    const int mt = (n + 15) / 16;   // 3125 row tiles
    const int gblk = (mt + 3) / 4;  // 782
    const int passBlks = 391;

    // phase2: passB + gemm1(+att1)
    phase2_kernel<<<passBlks + gblk, 256, 0, stream>>>(
        pairBuf, pairBase, bcur, offs, csr, NB, xb, w1p, h1b, asrc1, adst1, as1, ad1,
        n, passBlks);

    // fused gemm_res + gat1 (2 waves/node)
    const int g1Blks = (n + 1) / 2;  // 25000
    gat1_res_kernel<<<gblk + g1Blks, 256, 0, stream>>>(
        h1b, as1, ad1, offs, csr, b1, out1b, xb, wresp, bres, residb, n, gblk);

    gemm2_kernel<<<gblk, 256, 0, stream>>>(out1b, w2p, h2b, asrc2, adst2, as2, ad2, n);
    gat2_agg<<<(n + 3) / 4, 256, 0, stream>>>(h2b, as2, ad2, offs, csr, b2, out2b, part, n);
    bn_finalize<<<1, 128, 0, stream>>>(part, gamma, beta, ss, n);
    final_kernel<<<(n * 32 + 255) / 256, 256, 0, stream>>>(out2b, residb, ss, (float*)d_out, n);
}

// Round 14
// 163.902 us; speedup vs baseline: 1.5237x; 1.5237x over previous
//
#include <hip/hip_runtime.h>

#define NEG 0.2f
#define NEG_INF (-1e30f)

typedef __attribute__((ext_vector_type(8))) short bf16x8;
typedef __attribute__((ext_vector_type(4))) float f32x4;

__device__ __forceinline__ float leaky(float e) { return e > 0.f ? e : NEG * e; }

__device__ __forceinline__ unsigned short f2bf(float f) {
    unsigned int u = __float_as_uint(f);
    unsigned int r = u + 0x7fffu + ((u >> 16) & 1u);
    return (unsigned short)(r >> 16);
}
__device__ __forceinline__ float2 bf2f2(unsigned int u) {
    float2 r;
    r.x = __uint_as_float(u << 16);
    r.y = __uint_as_float(u & 0xffff0000u);
    return r;
}

// ---------------- fused prep: bucket-hist + x->bf16 + weight packing ----------------
__device__ __forceinline__ void pack_w(const float* __restrict__ W,
                                       unsigned short* __restrict__ Bp, int K, int N, int idx) {
    int i = idx & 7;
    int rest = idx >> 3;
    int lane = rest & 63;
    rest >>= 6;
    int KT = K / 32;
    int kt = rest % KT;
    int ct = rest / KT;
    int m = lane & 15, kb = lane >> 4;
    int k = kt * 32 + kb * 8 + i, col = ct * 16 + m;
    Bp[idx] = f2bf(W[(size_t)k * N + col]);
}

__global__ __launch_bounds__(256) void prep_kernel(const float* __restrict__ x,
                                                   unsigned short* __restrict__ xb, int n4,
                                                   const float* __restrict__ W1,
                                                   unsigned short* __restrict__ w1p,
                                                   const float* __restrict__ W2,
                                                   unsigned short* __restrict__ w2p,
                                                   const float* __restrict__ Wres,
                                                   unsigned short* __restrict__ wresp,
                                                   const int* __restrict__ dst, int E,
                                                   int* __restrict__ bucketCnt, int nbk,
                                                   int binBlks) {
    int b = blockIdx.x;
    if (b < binBlks) {
        __shared__ int hist[1600];
        for (int k = threadIdx.x; k < nbk; k += 256) hist[k] = 0;
        __syncthreads();
        int c0 = b * 4096;
        int cnt = min(4096, E - c0);
        for (int i = threadIdx.x; i < cnt; i += 256)
            atomicAdd(&hist[dst[c0 + i] >> 5], 1);
        __syncthreads();
        for (int k = threadIdx.x; k < nbk; k += 256) {
            int h = hist[k];
            if (h) atomicAdd(&bucketCnt[k], h);
        }
        return;
    }
    b -= binBlks;
    int nxb = (n4 + 255) / 256;
    if (b < nxb) {
        int i = b * 256 + threadIdx.x;
        if (i < n4) {
            float4 v = ((const float4*)x)[i];
            ushort4 o;
            o.x = f2bf(v.x); o.y = f2bf(v.y); o.z = f2bf(v.z); o.w = f2bf(v.w);
            ((ushort4*)xb)[i] = o;
        }
        return;
    }
    b -= nxb;
    if (b < 48) { pack_w(W1, w1p, 128, 96, b * 256 + threadIdx.x); return; }
    b -= 48;
    if (b < 48) { pack_w(W2, w2p, 96, 128, b * 256 + threadIdx.x); return; }
    b -= 48;
    if (b < 64) { pack_w(Wres, wresp, 128, 128, b * 256 + threadIdx.x); }
}

// ---------------- bucket scan (1563 elements, one block) + zero part ----------------
__global__ __launch_bounds__(1024) void scan_buckets(const int* __restrict__ bc,
                                                     int* __restrict__ pairBase,
                                                     int* __restrict__ bcur,
                                                     int* __restrict__ offs, int nbk, int n,
                                                     float* __restrict__ part) {
    __shared__ int buf[1024];
    __shared__ int carry;
    int tid = threadIdx.x;
    for (int i = tid; i < 64 * 256; i += 1024) part[i] = 0.f;
    if (tid == 0) carry = 0;
    __syncthreads();
    for (int base = 0; base < nbk; base += 1024) {
        int v = (base + tid < nbk) ? bc[base + tid] : 0;
        buf[tid] = v;
        __syncthreads();
        for (int s = 1; s < 1024; s <<= 1) {
            int t = (tid >= s) ? buf[tid - s] : 0;
            __syncthreads();
            buf[tid] += t;
            __syncthreads();
        }
        int incl = buf[tid];
        int tot = buf[1023];
        int c = carry;
        if (base + tid < nbk) {
            int ex = c + incl - v;  // exclusive prefix
            pairBase[base + tid] = ex;
            bcur[base + tid] = ex;
        }
        __syncthreads();
        if (tid == 0) carry = c + tot;
        __syncthreads();
    }
    if (tid == 0) {
        pairBase[nbk] = carry;
        offs[n] = carry;  // = E
    }
}

// ---------------- binned edge pass: LDS-staged bucket append ----------------
__global__ __launch_bounds__(256) void bin_kernel(const int* __restrict__ src,
                                                  const int* __restrict__ dst, int E,
                                                  int* __restrict__ bcur,
                                                  int2* __restrict__ pairBuf, int nb) {
    __shared__ int2 stage[4096];
    __shared__ int hist[1600];
    __shared__ int base[1600];
    for (int c0 = blockIdx.x * 4096; c0 < E; c0 += gridDim.x * 4096) {
        int cnt = min(4096, E - c0);
        for (int b = threadIdx.x; b < nb; b += 256) hist[b] = 0;
        __syncthreads();
        for (int i = threadIdx.x; i < cnt; i += 256) {
            int s = src[c0 + i], d = dst[c0 + i];
            stage[i] = make_int2(s, d);
            atomicAdd(&hist[d >> 5], 1);
        }
        __syncthreads();
        for (int b = threadIdx.x; b < nb; b += 256) {
            int h = hist[b];
            if (h) base[b] = atomicAdd(&bcur[b], h);
            hist[b] = 0;
        }
        __syncthreads();
        for (int i = threadIdx.x; i < cnt; i += 256) {
            int2 p = stage[i];
            int b = p.y >> 5;
            int off = atomicAdd(&hist[b], 1);
            pairBuf[base[b] + off] = p;
        }
        __syncthreads();
    }
}

// ---------------- MFMA GEMM body ----------------
template <int K, int N, int HEADS>
__device__ __forceinline__ void gemm_body(int w, const unsigned short* __restrict__ A,
                                          const unsigned short* __restrict__ Bp,
                                          const float* __restrict__ bias,
                                          unsigned short* __restrict__ outB,
                                          const float* __restrict__ asrc,
                                          const float* __restrict__ adst,
                                          float* __restrict__ a_s,
                                          float* __restrict__ a_d, int M) {
    constexpr int KT = K / 32, CT = N / 16;
    int row0 = w * 16;
    if (row0 >= M) return;
    int lane = threadIdx.x & 63;
    int m = lane & 15, kb = lane >> 4;
    const unsigned short* arow = A + (size_t)(row0 + m) * K + kb * 8;

    f32x4 acc[CT];
#pragma unroll
    for (int ct = 0; ct < CT; ++ct) acc[ct] = (f32x4){0.f, 0.f, 0.f, 0.f};

#pragma unroll
    for (int kt = 0; kt < KT; ++kt) {
        bf16x8 a = *(const bf16x8*)(arow + kt * 32);
#pragma unroll
        for (int ct = 0; ct < CT; ++ct) {
            bf16x8 b = *(const bf16x8*)(Bp + ((size_t)(ct * KT + kt) * 64 + lane) * 8);
            acc[ct] = __builtin_amdgcn_mfma_f32_16x16x32_bf16(a, b, acc[ct], 0, 0, 0);
        }
    }

#pragma unroll
    for (int r = 0; r < 4; ++r) {
        int row = row0 + kb * 4 + r;
#pragma unroll
        for (int ct = 0; ct < CT; ++ct) {
            int col = ct * 16 + m;
            float v = acc[ct][r] + (bias ? bias[col] : 0.f);
            outB[(size_t)row * N + col] = f2bf(v);
        }
    }

    if (HEADS > 0) {
        float asv[CT], adv[CT];
#pragma unroll
        for (int ct = 0; ct < CT; ++ct) {
            int col = ct * 16 + m;
            asv[ct] = asrc[col];
            adv[ct] = adst[col];
        }
        constexpr int TPH = CT / (HEADS > 0 ? HEADS : 1);
#pragma unroll
        for (int r = 0; r < 4; ++r) {
            int row = row0 + kb * 4 + r;
#pragma unroll
            for (int h = 0; h < HEADS; ++h) {
                float s = 0.f, d = 0.f;
#pragma unroll
                for (int t = 0; t < TPH; ++t) {
                    int ct = h * TPH + t;
                    s += acc[ct][r] * asv[ct];
                    d += acc[ct][r] * adv[ct];
                }
#pragma unroll
                for (int off = 1; off <= 8; off <<= 1) {
                    s += __shfl_xor(s, off);
                    d += __shfl_xor(d, off);
                }
                if (m == 0) {
                    a_s[(size_t)row * HEADS + h] = s;
                    a_d[(size_t)row * HEADS + h] = d;
                }
            }
        }
    }
}

// ---------------- phase2: passB (degree+offs+scatter) + gemm1 + gemm_res ----------------
__global__ __launch_bounds__(256) void phase2_kernel(
    const int2* __restrict__ pairBuf, const int* __restrict__ pairBase,
    const int* __restrict__ bcur, int* __restrict__ offs,
    int* __restrict__ csr, int nb,
    const unsigned short* __restrict__ xb,
    const unsigned short* __restrict__ w1p, unsigned short* __restrict__ h1b,
    const float* __restrict__ asrc1, const float* __restrict__ adst1,
    float* __restrict__ as1, float* __restrict__ ad1,
    const unsigned short* __restrict__ wresp, const float* __restrict__ bres,
    unsigned short* __restrict__ residb, int n, int passBlks, int g1Blks) {
    int b = blockIdx.x;
    int lane = threadIdx.x & 63;
    int wid = threadIdx.x >> 6;
    if (b < passBlks) {
        __shared__ int cnt[4][32];
        int bk = b * 4 + wid;
        if (bk < nb) {
            int node0 = bk * 32;
            int lo = pairBase[bk], hi = bcur[bk];
            if (lane < 32) cnt[wid][lane] = 0;
            for (int i = lo + lane; i < hi; i += 64)
                atomicAdd(&cnt[wid][pairBuf[i].y & 31], 1);
            int myc = (lane < 32) ? cnt[wid][lane] : 0;
            int c = myc;
#pragma unroll
            for (int s = 1; s < 32; s <<= 1) {
                int t = __shfl_up(c, s);
                if (lane >= s && lane < 32) c += t;
            }
            int basePos = lo + c - myc;
            if (lane < 32) {
                if (node0 + lane < n) offs[node0 + lane] = basePos;
                cnt[wid][lane] = basePos;
            }
            for (int i = lo + lane; i < hi; i += 64) {
                int2 p = pairBuf[i];
                int pos = atomicAdd(&cnt[wid][p.y & 31], 1);
                csr[pos] = p.x;
            }
        }
        return;
    }
    b -= passBlks;
    if (b < g1Blks) {
        gemm_body<128, 96, 3>(b * 4 + wid, xb, w1p, nullptr, h1b,
                              asrc1, adst1, as1, ad1, n);
        return;
    }
    b -= g1Blks;
    gemm_body<128, 128, 0>(b * 4 + wid, xb, wresp, bres, residb,
                           nullptr, nullptr, nullptr, nullptr, n);
}

// gemm2 standalone wrapper
__global__ __launch_bounds__(256) void gemm2_kernel(const unsigned short* __restrict__ A,
                                                    const unsigned short* __restrict__ Bp,
                                                    unsigned short* __restrict__ outB,
                                                    const float* __restrict__ asrc,
                                                    const float* __restrict__ adst,
                                                    float* __restrict__ a_s,
                                                    float* __restrict__ a_d, int M) {
    gemm_body<96, 128, 1>(blockIdx.x * 4 + (threadIdx.x >> 6), A, Bp, nullptr, outB,
                          asrc, adst, a_s, a_d, M);
}

// ---------------- GAT aggregation: 8-wide gather MLP (round-12 version) ----------------
__global__ __launch_bounds__(256) void gat1_agg(const unsigned short* __restrict__ h1b,
                                                const float* __restrict__ a_s,
                                                const float* __restrict__ a_d,
                                                const int* __restrict__ offs,
                                                const int* __restrict__ csr,
                                                const float* __restrict__ b1,
                                                unsigned short* __restrict__ out1b, int n) {
    __shared__ int ssrc[4][64];
    __shared__ float se[4][3][64];
    int wid = threadIdx.x >> 6;
    int node = blockIdx.x * 4 + wid;
    if (node >= n) return;
    int lane = threadIdx.x & 63;
    int head = lane >> 4; if (head > 2) head = 2;
    int beg = offs[node], end = offs[node + 1];
    int deg = end - beg;
    float ad0 = a_d[node * 3 + 0], ad1 = a_d[node * 3 + 1], ad2 = a_d[node * 3 + 2];
    float es0 = leaky(a_s[node * 3 + 0] + ad0);
    float es1 = leaky(a_s[node * 3 + 1] + ad1);
    float es2 = leaky(a_s[node * 3 + 2] + ad2);
    float2 hv0 = make_float2(0.f, 0.f);
    if (lane < 48) hv0 = bf2f2(*(const unsigned int*)&h1b[(size_t)node * 96 + 2 * lane]);

    float den;
    float2 acc;

    if (deg <= 64) {
        int s = 0;
        float l0 = NEG_INF, l1 = NEG_INF, l2 = NEG_INF;
        if (lane < deg) {
            s = csr[beg + lane];
            l0 = leaky(a_s[s * 3 + 0] + ad0);
            l1 = leaky(a_s[s * 3 + 1] + ad1);
            l2 = leaky(a_s[s * 3 + 2] + ad2);
        }
        float m0 = l0, m1 = l1, m2 = l2;
#pragma unroll
        for (int sh = 32; sh >= 1; sh >>= 1) {
            m0 = fmaxf(m0, __shfl_xor(m0, sh));
            m1 = fmaxf(m1, __shfl_xor(m1, sh));
            m2 = fmaxf(m2, __shfl_xor(m2, sh));
        }
        m0 = fmaxf(m0, es0); m1 = fmaxf(m1, es1); m2 = fmaxf(m2, es2);
        float e0 = 0.f, e1 = 0.f, e2 = 0.f;
        if (lane < deg) {
            e0 = __expf(l0 - m0); e1 = __expf(l1 - m1); e2 = __expf(l2 - m2);
        }
        ssrc[wid][lane] = s;
        se[wid][0][lane] = e0; se[wid][1][lane] = e1; se[wid][2][lane] = e2;
        float w0 = __expf(es0 - m0), w1 = __expf(es1 - m1), w2 = __expf(es2 - m2);
        den = (head == 0) ? w0 : ((head == 1) ? w1 : w2);
        float wSelf = (lane < 16) ? w0 : ((lane < 32) ? w1 : w2);
        acc.x = wSelf * hv0.x; acc.y = wSelf * hv0.y;

        int jj = 0;
        for (; jj + 7 < deg; jj += 8) {
            int sA[8]; float wA[8]; unsigned ph[8];
#pragma unroll
            for (int q = 0; q < 8; ++q) {
                sA[q] = ssrc[wid][jj + q];
                wA[q] = se[wid][head][jj + q];
            }
#pragma unroll
            for (int q = 0; q < 8; ++q)
                ph[q] = (lane < 48) ? *(const unsigned*)&h1b[(size_t)sA[q] * 96 + 2 * lane] : 0u;
            float dsum = 0.f;
#pragma unroll
            for (int q = 0; q < 8; ++q) {
                dsum += wA[q];
                if (lane < 48) {
                    float2 h = bf2f2(ph[q]);
                    acc.x += wA[q] * h.x; acc.y += wA[q] * h.y;
                }
            }
            den += dsum;
        }
        for (; jj + 3 < deg; jj += 4) {
            int sA[4]; float wA[4]; unsigned ph[4];
#pragma unroll
            for (int q = 0; q < 4; ++q) {
                sA[q] = ssrc[wid][jj + q];
                wA[q] = se[wid][head][jj + q];
            }
#pragma unroll
            for (int q = 0; q < 4; ++q)
                ph[q] = (lane < 48) ? *(const unsigned*)&h1b[(size_t)sA[q] * 96 + 2 * lane] : 0u;
            float dsum = 0.f;
#pragma unroll
            for (int q = 0; q < 4; ++q) {
                dsum += wA[q];
                if (lane < 48) {
                    float2 h = bf2f2(ph[q]);
                    acc.x += wA[q] * h.x; acc.y += wA[q] * h.y;
                }
            }
            den += dsum;
        }
        for (; jj < deg; ++jj) {
            int sA = ssrc[wid][jj];
            float wA = se[wid][head][jj];
            den += wA;
            if (lane < 48) {
                float2 ha = bf2f2(*(const unsigned*)&h1b[(size_t)sA * 96 + 2 * lane]);
                acc.x += wA * ha.x; acc.y += wA * ha.y;
            }
        }
    } else {
        float m0 = es0, m1 = es1, m2 = es2;
        for (int j = beg + lane; j < end; j += 64) {
            int s = csr[j];
            m0 = fmaxf(m0, leaky(a_s[s * 3 + 0] + ad0));
            m1 = fmaxf(m1, leaky(a_s[s * 3 + 1] + ad1));
            m2 = fmaxf(m2, leaky(a_s[s * 3 + 2] + ad2));
        }
#pragma unroll
        for (int sh = 32; sh >= 1; sh >>= 1) {
            m0 = fmaxf(m0, __shfl_xor(m0, sh));
            m1 = fmaxf(m1, __shfl_xor(m1, sh));
            m2 = fmaxf(m2, __shfl_xor(m2, sh));
        }
        float w0 = __expf(es0 - m0), w1 = __expf(es1 - m1), w2 = __expf(es2 - m2);
        den = (head == 0) ? w0 : ((head == 1) ? w1 : w2);
        float wSelf = (lane < 16) ? w0 : ((lane < 32) ? w1 : w2);
        acc.x = wSelf * hv0.x; acc.y = wSelf * hv0.y;
        for (int t0 = beg; t0 < end; t0 += 64) {
            int cnt = min(64, end - t0);
            int s = 0;
            float e0 = 0.f, e1 = 0.f, e2 = 0.f;
            if (lane < cnt) {
                s = csr[t0 + lane];
                e0 = __expf(leaky(a_s[s * 3 + 0] + ad0) - m0);
                e1 = __expf(leaky(a_s[s * 3 + 1] + ad1) - m1);
                e2 = __expf(leaky(a_s[s * 3 + 2] + ad2) - m2);
            }
            ssrc[wid][lane] = s;
            se[wid][0][lane] = e0; se[wid][1][lane] = e1; se[wid][2][lane] = e2;
            int jj = 0;
            for (; jj + 7 < cnt; jj += 8) {
                int sA[8]; float wA[8]; unsigned ph[8];
#pragma unroll
                for (int q = 0; q < 8; ++q) {
                    sA[q] = ssrc[wid][jj + q];
                    wA[q] = se[wid][head][jj + q];
                }
#pragma unroll
                for (int q = 0; q < 8; ++q)
                    ph[q] = (lane < 48) ? *(const unsigned*)&h1b[(size_t)sA[q] * 96 + 2 * lane] : 0u;
                float dsum = 0.f;
#pragma unroll
                for (int q = 0; q < 8; ++q) {
                    dsum += wA[q];
                    if (lane < 48) {
                        float2 h = bf2f2(ph[q]);
                        acc.x += wA[q] * h.x; acc.y += wA[q] * h.y;
                    }
                }
                den += dsum;
            }
            for (; jj < cnt; ++jj) {
                int sA = ssrc[wid][jj];
                float wA = se[wid][head][jj];
                den += wA;
                if (lane < 48) {
                    float2 ha = bf2f2(*(const unsigned*)&h1b[(size_t)sA * 96 + 2 * lane]);
                    acc.x += wA * ha.x; acc.y += wA * ha.y;
                }
            }
        }
    }

    if (lane < 48) {
        float inv = 1.f / (den + 1e-16f);
        ushort2 o;
        o.x = f2bf(acc.x * inv + b1[2 * lane]);
        o.y = f2bf(acc.y * inv + b1[2 * lane + 1]);
        *(ushort2*)&out1b[(size_t)node * 96 + 2 * lane] = o;
    }
}

// gat2: 128 ch, 1 head; writes bf16 out2 AND accumulates BN partial sums.
__global__ __launch_bounds__(256) void gat2_agg(const unsigned short* __restrict__ h2b,
                                                const float* __restrict__ a_s,
                                                const float* __restrict__ a_d,
                                                const int* __restrict__ offs,
                                                const int* __restrict__ csr,
                                                const float* __restrict__ b2,
                                                unsigned short* __restrict__ out2b,
                                                float* __restrict__ part, int n) {
    __shared__ int ssrc[4][64];
    __shared__ float se[4][64];
    __shared__ float4 red[4][64];
    int wid = threadIdx.x >> 6;
    int node = blockIdx.x * 4 + wid;
    int lane = threadIdx.x & 63;
    float2 o = make_float2(0.f, 0.f);

    if (node < n) {
        int beg = offs[node], end = offs[node + 1];
        int deg = end - beg;
        float ad = a_d[node];
        float es = leaky(a_s[node] + ad);
        float2 hv0 = bf2f2(*(const unsigned int*)&h2b[(size_t)node * 128 + 2 * lane]);
        float den;
        float2 acc;

        if (deg <= 64) {
            int s = 0;
            float l = NEG_INF;
            if (lane < deg) {
                s = csr[beg + lane];
                l = leaky(a_s[s] + ad);
            }
            float m = l;
#pragma unroll
            for (int sh = 32; sh >= 1; sh >>= 1) m = fmaxf(m, __shfl_xor(m, sh));
            m = fmaxf(m, es);
            float e = (lane < deg) ? __expf(l - m) : 0.f;
            ssrc[wid][lane] = s;
            se[wid][lane] = e;
            float wSelf = __expf(es - m);
            den = wSelf;
            acc.x = wSelf * hv0.x; acc.y = wSelf * hv0.y;

            int jj = 0;
            for (; jj + 7 < deg; jj += 8) {
                int sA[8]; float wA[8]; unsigned ph[8];
#pragma unroll
                for (int q = 0; q < 8; ++q) {
                    sA[q] = ssrc[wid][jj + q];
                    wA[q] = se[wid][jj + q];
                }
#pragma unroll
                for (int q = 0; q < 8; ++q)
                    ph[q] = *(const unsigned*)&h2b[(size_t)sA[q] * 128 + 2 * lane];
                float dsum = 0.f;
#pragma unroll
                for (int q = 0; q < 8; ++q) {
                    dsum += wA[q];
                    float2 h = bf2f2(ph[q]);
                    acc.x += wA[q] * h.x; acc.y += wA[q] * h.y;
                }
                den += dsum;
            }
            for (; jj + 3 < deg; jj += 4) {
                int sA[4]; float wA[4]; unsigned ph[4];
#pragma unroll
                for (int q = 0; q < 4; ++q) {
                    sA[q] = ssrc[wid][jj + q];
                    wA[q] = se[wid][jj + q];
                }
#pragma unroll
                for (int q = 0; q < 4; ++q)
                    ph[q] = *(const unsigned*)&h2b[(size_t)sA[q] * 128 + 2 * lane];
                float dsum = 0.f;
#pragma unroll
                for (int q = 0; q < 4; ++q) {
                    dsum += wA[q];
                    float2 h = bf2f2(ph[q]);
                    acc.x += wA[q] * h.x; acc.y += wA[q] * h.y;
                }
                den += dsum;
            }
            for (; jj < deg; ++jj) {
                int sA = ssrc[wid][jj];
                float wA = se[wid][jj];
                den += wA;
                float2 ha = bf2f2(*(const unsigned*)&h2b[(size_t)sA * 128 + 2 * lane]);
                acc.x += wA * ha.x; acc.y += wA * ha.y;
            }
        } else {
            float m = es;
            for (int j = beg + lane; j < end; j += 64) {
                int s = csr[j];
                m = fmaxf(m, leaky(a_s[s] + ad));
            }
#pragma unroll
            for (int sh = 32; sh >= 1; sh >>= 1) m = fmaxf(m, __shfl_xor(m, sh));
            float wSelf = __expf(es - m);
            den = wSelf;
            acc.x = wSelf * hv0.x; acc.y = wSelf * hv0.y;
            for (int t0 = beg; t0 < end; t0 += 64) {
                int cnt = min(64, end - t0);
                int s = 0;
                float e = 0.f;
                if (lane < cnt) {
                    s = csr[t0 + lane];
                    e = __expf(leaky(a_s[s] + ad) - m);
                }
                ssrc[wid][lane] = s;
                se[wid][lane] = e;
                int jj = 0;
                for (; jj + 7 < cnt; jj += 8) {
                    int sA[8]; float wA[8]; unsigned ph[8];
#pragma unroll
                    for (int q = 0; q < 8; ++q) {
                        sA[q] = ssrc[wid][jj + q];
                        wA[q] = se[wid][jj + q];
                    }
#pragma unroll
                    for (int q = 0; q < 8; ++q)
                        ph[q] = *(const unsigned*)&h2b[(size_t)sA[q] * 128 + 2 * lane];
                    float dsum = 0.f;
#pragma unroll
                    for (int q = 0; q < 8; ++q) {
                        dsum += wA[q];
                        float2 h = bf2f2(ph[q]);
                        acc.x += wA[q] * h.x; acc.y += wA[q] * h.y;
                    }
                    den += dsum;
                }
                for (; jj < cnt; ++jj) {
                    int sA = ssrc[wid][jj];
                    float wA = se[wid][jj];
                    den += wA;
                    float2 ha = bf2f2(*(const unsigned*)&h2b[(size_t)sA * 128 + 2 * lane]);
                    acc.x += wA * ha.x; acc.y += wA * ha.y;
                }
            }
        }

        float inv = 1.f / (den + 1e-16f);
        o.x = acc.x * inv + b2[2 * lane];
        o.y = acc.y * inv + b2[2 * lane + 1];
        ushort2 ob;
        ob.x = f2bf(o.x); ob.y = f2bf(o.y);
        *(ushort2*)&out2b[(size_t)node * 128 + 2 * lane] = ob;
    }

    // ---- block-level BN partial reduction ----
    red[wid][lane] = make_float4(o.x, o.y, o.x * o.x, o.y * o.y);
    __syncthreads();
    if (wid == 0) {
        float4 a = red[0][lane], b = red[1][lane], c = red[2][lane], d = red[3][lane];
        float sx = a.x + b.x + c.x + d.x;
        float sy = a.y + b.y + c.y + d.y;
        float qx = a.z + b.z + c.z + d.z;
        float qy = a.w + b.w + c.w + d.w;
        float* p = part + (size_t)(blockIdx.x & 63) * 256;
        atomicAdd(&p[2 * lane + 0], sx);
        atomicAdd(&p[2 * lane + 1], sy);
        atomicAdd(&p[128 + 2 * lane + 0], qx);
        atomicAdd(&p[128 + 2 * lane + 1], qy);
    }
}

// ---------------- BN finalize ----------------
__global__ void bn_finalize(const float* __restrict__ part, const float* __restrict__ gamma,
                            const float* __restrict__ beta, float* __restrict__ ss, int n) {
    int c = threadIdx.x;  // 128
    float S = 0.f, Q = 0.f;
    for (int k = 0; k < 64; ++k) {
        S += part[(size_t)k * 256 + c];
        Q += part[(size_t)k * 256 + 128 + c];
    }
    float invN = 1.f / (float)n;
    float mu = S * invN;
    float var = Q * invN - mu * mu;
    float g = gamma[c] * rsqrtf(var + 1e-5f);
    ss[c] = g;
    ss[128 + c] = beta[c] - mu * g;
}

// ---------------- fused BN-normalize + ReLU + residual ----------------
__global__ void final_kernel(const unsigned short* __restrict__ out2b,
                             const unsigned short* __restrict__ residb,
                             const float* __restrict__ ss, float* __restrict__ out, int n) {
    int i = blockIdx.x * blockDim.x + threadIdx.x;
    if (i >= n * 32) return;
    int c0 = (i & 31) * 4;
    uint2 v = ((const uint2*)out2b)[i];
    uint2 r = ((const uint2*)residb)[i];
    float2 v01 = bf2f2(v.x), v23 = bf2f2(v.y);
    float2 r01 = bf2f2(r.x), r23 = bf2f2(r.y);
    float4 o;
    o.x = fmaxf(v01.x * ss[c0 + 0] + ss[128 + c0 + 0], 0.f) + r01.x;
    o.y = fmaxf(v01.y * ss[c0 + 1] + ss[128 + c0 + 1], 0.f) + r01.y;
    o.z = fmaxf(v23.x * ss[c0 + 2] + ss[128 + c0 + 2], 0.f) + r23.x;
    o.w = fmaxf(v23.y * ss[c0 + 3] + ss[128 + c0 + 3], 0.f) + r23.y;
    ((float4*)out)[i] = o;
}

extern "C" void kernel_launch(void* const* d_in, const int* in_sizes, int n_in,
                              void* d_out, int out_size, void* d_ws, size_t ws_size,
                              hipStream_t stream) {
    const float* x     = (const float*)d_in[0];
    const int*   ei    = (const int*)d_in[1];
    const float* W1    = (const float*)d_in[2];
    const float* asrc1 = (const float*)d_in[3];
    const float* adst1 = (const float*)d_in[4];
    const float* b1    = (const float*)d_in[5];
    const float* W2    = (const float*)d_in[6];
    const float* asrc2 = (const float*)d_in[7];
    const float* adst2 = (const float*)d_in[8];
    const float* b2    = (const float*)d_in[9];
    const float* gamma = (const float*)d_in[10];
    const float* beta  = (const float*)d_in[11];
    const float* Wres  = (const float*)d_in[12];
    const float* bres  = (const float*)d_in[13];

    const int n = in_sizes[0] / 128;  // 50000
    const int E = in_sizes[1] / 2;    // 800000

    char* ws = (char*)d_ws;
    size_t off = 0;
    auto alloc = [&](size_t bytes) {
        void* p = ws + off;
        off = (off + bytes + 255) & ~(size_t)255;
        return p;
    };
    float* as1  = (float*)alloc((size_t)n * 3 * 4);
    float* ad1  = (float*)alloc((size_t)n * 3 * 4);
    float* as2  = (float*)alloc((size_t)n * 4);
    float* ad2  = (float*)alloc((size_t)n * 4);
    float* part = (float*)alloc(64 * 256 * 4);
    float* ss   = (float*)alloc(256 * 4);
    unsigned short* xb     = (unsigned short*)alloc((size_t)n * 128 * 2);
    unsigned short* h1b    = (unsigned short*)alloc((size_t)n * 96 * 2);
    unsigned short* h2b    = (unsigned short*)alloc((size_t)n * 128 * 2);
    unsigned short* out1b  = (unsigned short*)alloc((size_t)n * 96 * 2);
    unsigned short* out2b  = (unsigned short*)alloc((size_t)n * 128 * 2);
    unsigned short* residb = (unsigned short*)alloc((size_t)n * 128 * 2);
    unsigned short* w1p    = (unsigned short*)alloc(128 * 96 * 2);
    unsigned short* w2p    = (unsigned short*)alloc(96 * 128 * 2);
    unsigned short* wresp  = (unsigned short*)alloc(128 * 128 * 2);
    int* offs      = (int*)alloc((size_t)(n + 1) * 4);
    int* bucketCnt = (int*)alloc(1600 * 4);
    int* pairBase  = (int*)alloc(1601 * 4);
    int* bcur      = (int*)alloc(1600 * 4);
    int2* pairBuf  = (int2*)alloc((size_t)E * 8);
    int* csr       = (int*)alloc((size_t)E * 4);

    hipMemsetAsync(bucketCnt, 0, 1600 * 4, stream);

    const int* srcIdx = ei;
    const int* dstIdx = ei + E;
    const int NB = (n + 31) / 32;           // 1563 buckets
    const int binBlks = (E + 4095) / 4096;  // 196

    const int nxb = (n * 32 + 255) / 256;
    prep_kernel<<<binBlks + nxb + 160, 256, 0, stream>>>(x, xb, n * 32, W1, w1p, W2, w2p,
                                                         Wres, wresp, dstIdx, E,
                                                         bucketCnt, NB, binBlks);

    scan_buckets<<<1, 1024, 0, stream>>>(bucketCnt, pairBase, bcur, offs, NB, n, part);

    bin_kernel<<<binBlks, 256, 0, stream>>>(srcIdx, dstIdx, E, bcur, pairBuf, NB);

    const int mt = (n + 15) / 16;   // 3125 row tiles
    const int gblk = (mt + 3) / 4;  // 782
    const int passBlks = 391;

    // phase2: passB (degree+offs+scatter) + gemm1(+att1) + gemm_res
    phase2_kernel<<<passBlks + 2 * gblk, 256, 0, stream>>>(
        pairBuf, pairBase, bcur, offs, csr, NB, xb, w1p, h1b, asrc1, adst1, as1, ad1,
        wresp, bres, residb, n, passBlks, gblk);

    gat1_agg<<<(n + 3) / 4, 256, 0, stream>>>(h1b, as1, ad1, offs, csr, b1, out1b, n);
    gemm2_kernel<<<gblk, 256, 0, stream>>>(out1b, w2p, h2b, asrc2, adst2, as2, ad2, n);
    gat2_agg<<<(n + 3) / 4, 256, 0, stream>>>(h2b, as2, ad2, offs, csr, b2, out2b, part, n);
    bn_finalize<<<1, 128, 0, stream>>>(part, gamma, beta, ss, n);
    final_kernel<<<(n * 32 + 255) / 256, 256, 0, stream>>>(out2b, residb, ss, (float*)d_out, n);
}